// Round 1
// baseline (294.843 us; speedup 1.0000x reference)
//
#include <hip/hip_runtime.h>

#define Bq   32
#define Lq   4096
#define Eq   1024
#define OUTq 64
#define NW   16   // waves per mm block
#define TG   8    // rows per group in mm kernel

// ---------------------------------------------------------------------------
// K1: vec[b][e] = dot(inputA[b], W1a[e]) + b1a[e] + dot(inputB[b], W1b[e]) + b1b[e]
// One wave per (b, 8 consecutive e). Input rows held in registers, W rows
// streamed coalesced (float4), wave shuffle reduction.
// ---------------------------------------------------------------------------
__global__ __launch_bounds__(256) void vec_kernel(
    const float* __restrict__ inA, const float* __restrict__ inB,
    const float* __restrict__ W1a, const float* __restrict__ b1a,
    const float* __restrict__ W1b, const float* __restrict__ b1b,
    float* __restrict__ vec)
{
    int wid  = (blockIdx.x * blockDim.x + threadIdx.x) >> 6;  // global wave id
    int lane = threadIdx.x & 63;
    int b    = wid & (Bq - 1);
    int e0   = (wid >> 5) << 3;   // 8 e's per wave
    if (e0 >= Eq) return;

    const float4* a4  = (const float4*)(inA + (size_t)b * Eq);
    const float4* bb4 = (const float4*)(inB + (size_t)b * Eq);
    float4 ar[4], br[4];
#pragma unroll
    for (int j = 0; j < 4; ++j) { ar[j] = a4[lane + 64 * j]; br[j] = bb4[lane + 64 * j]; }

#pragma unroll
    for (int k = 0; k < 8; ++k) {
        int e = e0 + k;
        const float4* wa = (const float4*)(W1a + (size_t)e * Eq);
        const float4* wb = (const float4*)(W1b + (size_t)e * Eq);
        float acc = 0.f;
#pragma unroll
        for (int j = 0; j < 4; ++j) {
            float4 w = wa[lane + 64 * j];
            acc += ar[j].x * w.x + ar[j].y * w.y + ar[j].z * w.z + ar[j].w * w.w;
            float4 v = wb[lane + 64 * j];
            acc += br[j].x * v.x + br[j].y * v.y + br[j].z * v.z + br[j].w * v.w;
        }
#pragma unroll
        for (int s = 32; s; s >>= 1) acc += __shfl_xor(acc, s, 64);
        if (lane == 0) vec[(size_t)b * Eq + e] = acc + b1a[e] + b1b[e];
    }
}

// ---------------------------------------------------------------------------
// K3: pure copy of cache rows t in [start_row, L) into new_cache.
// grid.y = batch, grid.x covers the per-batch float4 range, 4 f4/thread.
// ---------------------------------------------------------------------------
__global__ __launch_bounds__(256) void copy_kernel(
    const float* __restrict__ src, float* __restrict__ dst,
    int start_row, int f4_per_b)
{
    int b = blockIdx.y;
    int base = blockIdx.x * 1024 + threadIdx.x;
    size_t rowbase = ((size_t)b * Lq + start_row) * (Eq / 4);
    const float4* s4 = (const float4*)src;
    float4* d4 = (float4*)dst;
#pragma unroll
    for (int j = 0; j < 4; ++j) {
        int r4 = base + j * 256;
        if (r4 < f4_per_b) d4[rowbase + r4] = s4[rowbase + r4];
    }
}

// ---------------------------------------------------------------------------
// K2: fused copy + GEMM for rows t in [0, cache_len].
//   out[b,t,o] = row . W2[o,:] + b2[o];  new_cache[b,t,:] = row
//   row = cache[b,t,:]  (t < cache_len)  or  vec[b,:]  (t == cache_len)
// 1024 threads = 16 waves. lane = o. Wave w owns K-slice [64w, 64w+64),
// W2 slice resident in 64 VGPRs. Rows staged in LDS, consumed via
// uniform-address (broadcast) ds_read_b128. Cross-wave reduce via LDS.
// Next group's global loads prefetched into VGPRs before the barriers.
// ---------------------------------------------------------------------------
__global__ __launch_bounds__(1024) void mm_kernel(
    const float* __restrict__ cache, const float* __restrict__ vec,
    const float* __restrict__ W2, const float* __restrict__ b2,
    float* __restrict__ outp, float* __restrict__ ncache, int cache_len)
{
    const int rows_per_b = cache_len + 1;           // 2049
    const int total_rows = Bq * rows_per_b;         // 65568
    const int n_groups = (total_rows + TG - 1) / TG;

    __shared__ float rowbuf[TG][Eq];                // 32 KB
    __shared__ float part[NW][TG * 64];             // 32 KB

    const int tid = threadIdx.x;
    const int w = tid >> 6, lane = tid & 63;

    // W2 slice: lane (=o) holds W2[o][64w + k], k=0..63, as 16 float4
    float4 w2r[16];
#pragma unroll
    for (int j = 0; j < 16; ++j)
        w2r[j] = *(const float4*)(W2 + (size_t)lane * Eq + 64 * w + 4 * j);

    const int rsub = tid >> 7;   // 0..7 : row within group
    const int c    = tid & 127;  // thread covers float4 indices c and c+128

    auto load_group = [&](int gg, float4& l0, float4& l1) {
        int row = gg * TG + rsub;
        if (row >= total_rows) row = total_rows - 1;   // clamp (tail safety)
        int bb = row / rows_per_b;
        int t  = row - bb * rows_per_b;
        const float* src = (t == cache_len) ? (vec + (size_t)bb * Eq)
                                            : (cache + ((size_t)bb * Lq + t) * Eq);
        l0 = *(const float4*)(src + 4 * c);
        l1 = *(const float4*)(src + 4 * (c + 128));
    };

    int g = blockIdx.x;
    float4 ld0, ld1;
    if (g < n_groups) load_group(g, ld0, ld1);

    for (; g < n_groups; g += gridDim.x) {
        // ---- phase 1: copy-store + LDS stage + prefetch next group ----
        int row = g * TG + rsub;
        if (row < total_rows) {
            int bb = row / rows_per_b;
            int t  = row - bb * rows_per_b;
            float* dst = ncache + ((size_t)bb * Lq + t) * Eq;
            *(float4*)(dst + 4 * c)         = ld0;
            *(float4*)(dst + 4 * (c + 128)) = ld1;
        }
        *(float4*)(&rowbuf[rsub][4 * c])         = ld0;
        *(float4*)(&rowbuf[rsub][4 * (c + 128)]) = ld1;

        int gn = g + gridDim.x;
        if (gn < n_groups) load_group(gn, ld0, ld1);

        __syncthreads();   // A: rowbuf ready

        // ---- phase 2: per-wave K-slice FMAs ----
#pragma unroll
        for (int r = 0; r < TG; ++r) {
            float acc = 0.f;
#pragma unroll
            for (int j = 0; j < 16; ++j) {
                float4 rv = *(const float4*)(&rowbuf[r][64 * w + 4 * j]); // broadcast
                acc += rv.x * w2r[j].x + rv.y * w2r[j].y +
                       rv.z * w2r[j].z + rv.w * w2r[j].w;
            }
            part[w][r * 64 + lane] = acc;
        }
        __syncthreads();   // B: partials ready

        // ---- phase 3: cross-wave reduce + out store ----
        if (tid < TG * 64) {
            float s = 0.f;
#pragma unroll
            for (int ww = 0; ww < NW; ++ww) s += part[ww][tid];
            int rr = tid >> 6, o = tid & 63;
            int row2 = g * TG + rr;
            if (row2 < total_rows) {
                int bb = row2 / rows_per_b;
                int t  = row2 - bb * rows_per_b;
                outp[((size_t)bb * rows_per_b + t) * OUTq + o] = s + b2[o];
            }
        }
        __syncthreads();   // C: part free for next group
    }
}

// ---------------------------------------------------------------------------
extern "C" void kernel_launch(void* const* d_in, const int* in_sizes, int n_in,
                              void* d_out, int out_size, void* d_ws, size_t ws_size,
                              hipStream_t stream)
{
    const float* inA   = (const float*)d_in[0];
    const float* inB   = (const float*)d_in[1];
    const float* cache = (const float*)d_in[2];
    const float* W1a   = (const float*)d_in[3];
    const float* b1a   = (const float*)d_in[4];
    const float* W1b   = (const float*)d_in[5];
    const float* b1b   = (const float*)d_in[6];
    const float* W2    = (const float*)d_in[7];
    const float* b2v   = (const float*)d_in[8];

    float* outp = (float*)d_out;
    // out is (B, cache_len+1, OUT) then new_cache (B, L, E), both f32, concat.
    int rows_per_b = (out_size - Bq * Lq * Eq) / (Bq * OUTq);  // cache_len + 1
    int cache_len  = rows_per_b - 1;                           // 2048
    float* ncache  = outp + (size_t)Bq * rows_per_b * OUTq;
    float* vec     = (float*)d_ws;                             // 32*1024 f32

    // K1: vec
    vec_kernel<<<dim3(1024), dim3(256), 0, stream>>>(inA, inB, W1a, b1a, W1b, b1b, vec);

    // K3: pure copy of rows t in [cache_len+1, L)
    int start_row = cache_len + 1;
    int f4_per_b  = (Lq - start_row) * (Eq / 4);
    if (f4_per_b > 0) {
        dim3 cg((f4_per_b + 1023) / 1024, Bq);
        copy_kernel<<<cg, dim3(256), 0, stream>>>(cache, ncache, start_row, f4_per_b);
    }

    // K2: fused copy + GEMM for rows t in [0, cache_len]
    mm_kernel<<<dim3(256), dim3(1024), 0, stream>>>(cache, vec, W2, b2v,
                                                    outp, ncache, cache_len);
}